// Round 7
// baseline (233.652 us; speedup 1.0000x reference)
//
#include <hip/hip_runtime.h>
#include <stdint.h>
#include <stddef.h>

// Problem constants
#define BB 8
#define CC 16
#define DD 192
#define OCC 4
#define OHH 50
#define OWW 200

#define LDP 200   // padded LDS row stride in bf16 elements (192 + 8)
#define CH  24    // 8-element chunks per 192 row

typedef __attribute__((ext_vector_type(8))) short s8v;   // 8 bf16 = 16B (MFMA A/B frag, 4 VGPRs)
typedef __attribute__((ext_vector_type(4))) short s4v;   // 4 bf16 = 8B
typedef __attribute__((ext_vector_type(4))) float f4v;   // 4 fp32
typedef __attribute__((ext_vector_type(4))) float f32x4; // MFMA C/D frag

__device__ __forceinline__ short rne_bf16(float f) {
  uint32_t u = __float_as_uint(f);
  u += 0x7fffu + ((u >> 16) & 1u);
  return (short)(u >> 16);
}
__device__ __forceinline__ float bf2f(short s) {
  return __uint_as_float(((uint32_t)(uint16_t)s) << 16);
}

// ---------------- prep_all ----------------
// Branch 0 [0,256):    R frag-swizzle via LDS. Rs[ij][mt(12)][kc(6)][lane(64)][8]:
//                      elem(lane,t) = R[ij][mt*16+(lane&15)][kc*32+(lane>>4)*8+t]
// Branch 1 [256,384):  X frag-swizzle (A-layout, transposing). Xs[bj][qt][kc][lane][8]:
//                      elem(lane,t) = x[bj][kc*32+(lane>>4)*8+t][qt*16+(lane&15)]
// Branch 2:            P linear cvt
// Branch 3:            PT transpose -> PTTb[outer][n][q]
#define PREP_RS_BLK 256
#define PREP_XS_BLK 128
#define PREP_P_BLK 600
#define PREP_PT_BLK 2688
#define PREP_TOTAL (PREP_RS_BLK + PREP_XS_BLK + PREP_P_BLK + PREP_PT_BLK)

__global__ __launch_bounds__(256) void prep_all(const float* __restrict__ R, short* __restrict__ Rs,
                                                const float* __restrict__ x, short* __restrict__ Xs,
                                                const float* __restrict__ P, short* __restrict__ Pb,
                                                const float* __restrict__ PT, short* __restrict__ PTTb) {
  __shared__ __align__(16) short stage[DD * LDP];  // 76.8 KB (aliased as float for PT branch)
  const int blk = blockIdx.x;
  const int tid = threadIdx.x;

  if (blk < PREP_RS_BLK) {
    const int ij = blk;
    // stage-in: coalesced fp32 rows -> bf16 natural [m][p]
    const f4v* src = (const f4v*)(R + (size_t)ij * DD * DD);
    for (int c = tid; c < DD * 48; c += 256) {
      int row = c / 48, c4 = c % 48;
      f4v v = src[c];
      s4v o;
      #pragma unroll
      for (int r = 0; r < 4; ++r) o[r] = rne_bf16(v[r]);
      *(s4v*)(&stage[row * LDP + c4 * 4]) = o;
    }
    __syncthreads();
    // emit frags, coalesced 16B/thread
    short* dst = Rs + (size_t)ij * 4608 * 8;
    #pragma unroll
    for (int s = 0; s < 18; ++s) {
      int g = s * 256 + tid;
      int lane = g & 63, fi = g >> 6;
      int kc = fi % 6, mt = fi / 6;
      s8v v = *(const s8v*)(&stage[(mt * 16 + (lane & 15)) * LDP + kc * 32 + ((lane >> 4) << 3)]);
      *(s8v*)(dst + (size_t)g * 8) = v;
    }
    return;
  }
  if (blk < PREP_RS_BLK + PREP_XS_BLK) {
    const int bj = blk - PREP_RS_BLK;
    // stage-in: coalesced fp32 rows -> bf16 natural [p][q]
    const f4v* src = (const f4v*)(x + (size_t)bj * DD * DD);
    for (int c = tid; c < DD * 48; c += 256) {
      int row = c / 48, c4 = c % 48;
      f4v v = src[c];
      s4v o;
      #pragma unroll
      for (int r = 0; r < 4; ++r) o[r] = rne_bf16(v[r]);
      *(s4v*)(&stage[row * LDP + c4 * 4]) = o;
    }
    __syncthreads();
    // emit A-layout frags (transposed gather from LDS), coalesced 16B/thread writes
    short* dst = Xs + (size_t)bj * 4608 * 8;
    #pragma unroll
    for (int s = 0; s < 18; ++s) {
      int g = s * 256 + tid;
      int lane = g & 63, fi = g >> 6;
      int kc = fi % 6, qt = fi / 6;
      int q = qt * 16 + (lane & 15);
      int p0 = kc * 32 + ((lane >> 4) << 3);
      s8v o;
      #pragma unroll
      for (int t = 0; t < 8; ++t) o[t] = stage[(p0 + t) * LDP + q];
      *(s8v*)(dst + (size_t)g * 8) = o;
    }
    return;
  }
  if (blk < PREP_RS_BLK + PREP_XS_BLK + PREP_P_BLK) {
    int idx = (blk - PREP_RS_BLK - PREP_XS_BLK) * 256 + tid;
    f4v v = *(const f4v*)(P + (size_t)idx * 4);
    s4v o;
    #pragma unroll
    for (int r = 0; r < 4; ++r) o[r] = rne_bf16(v[r]);
    *(s4v*)(Pb + (size_t)idx * 4) = o;
    return;
  }
  {
    float* ftile = (float*)stage;  // [32][33]
    const int tx = tid & 31, ty = tid >> 5;
    int t = blk - (PREP_RS_BLK + PREP_XS_BLK + PREP_P_BLK);
    int outer = t / 42, rem = t % 42;
    int q0 = (rem / 7) * 32, n0 = (rem % 7) * 32;
    const float* src = PT + (size_t)outer * DD * OWW;
    for (int r = ty; r < 32; r += 8)
      ftile[r * 33 + tx] = (n0 + tx < OWW) ? src[(size_t)(q0 + r) * OWW + n0 + tx] : 0.f;
    __syncthreads();
    short* dst = PTTb + (size_t)outer * OWW * DD;
    for (int r = ty; r < 32; r += 8)
      if (n0 + r < OWW) dst[(size_t)(n0 + r) * DD + q0 + tx] = rne_bf16(ftile[tx * 33 + r]);
  }
}

// ---------------- stage A ----------------
// y[b,i] = sum_j R[i,j] @ x[b,j] @ R[i,j]^T, split over jg halves.
// Both mm1 operands are coalesced 1KB frag loads from global (L2/L3-resident Rs/Xs).
// LDS holds only double-buffered T -> ONE barrier per j.
//   mm1: T^T[q][m] = sum_p Xfrag[q][p] Rfrag[m][p]   -> pack T[m][q] into buf(j&1)
//   mm2: y[m][n]  += sum_q T[m][q] Rfrag[n][q]       (T rows from LDS)
// WAR: pack[j] writes buf(j&1); its prior readers mm2[j-2] are fenced by barrier(j-1).
// 1024 threads, __launch_bounds__(1024,2) -> VGPR cap 128 (empirical: cap = 256/n).
__global__ __launch_bounds__(1024, 2) void stageA(const short* __restrict__ Rs,
                                                  const short* __restrict__ Xs,
                                                  short* __restrict__ ypart) {
  __shared__ __align__(16) short ldsT[2 * DD * LDP];  // 153.6 KB -> 1 block/CU
  const int tid = threadIdx.x;
  const int bx = blockIdx.x;
  const int b = bx >> 5, i = (bx >> 1) & 15, jg = bx & 1;
  const int lane15 = tid & 15, quad = (tid & 63) >> 4;
  const int lane = tid & 63;
  const int wid = tid >> 6;   // 0..15
  const int wq = wid >> 2;    // 0..3 : A-dim, 3 tiles each
  const int wm = wid & 3;     // 0..3 : B-dim, 3 tiles each

  f32x4 acc_y[3][3];
  #pragma unroll
  for (int a = 0; a < 3; ++a)
    #pragma unroll
    for (int c = 0; c < 3; ++c) acc_y[a][c] = (f32x4){0.f, 0.f, 0.f, 0.f};

  for (int jj = 0; jj < 8; ++jj) {
    const short* xt = Xs + (size_t)(b * CC + jg * 8 + jj) * (4608 * 8);
    const short* rt = Rs + (size_t)(i * CC + jg * 8 + jj) * (4608 * 8);
    short* buf = ldsT + (jj & 1) * (DD * LDP);

    // mm1: both operands from global frags
    f32x4 acc_t[3][3];
    #pragma unroll
    for (int a = 0; a < 3; ++a)
      #pragma unroll
      for (int c = 0; c < 3; ++c) acc_t[a][c] = (f32x4){0.f, 0.f, 0.f, 0.f};

    #pragma unroll
    for (int kc = 0; kc < 6; ++kc) {
      s8v af[3], bf[3];
      #pragma unroll
      for (int a = 0; a < 3; ++a)
        af[a] = *(const s8v*)(xt + (size_t)(((wq * 3 + a) * 6 + kc) * 512) + lane * 8);
      #pragma unroll
      for (int c = 0; c < 3; ++c)
        bf[c] = *(const s8v*)(rt + (size_t)(((wm * 3 + c) * 6 + kc) * 512) + lane * 8);
      #pragma unroll
      for (int a = 0; a < 3; ++a)
        #pragma unroll
        for (int c = 0; c < 3; ++c)
          acc_t[a][c] = __builtin_amdgcn_mfma_f32_16x16x32_bf16(af[a], bf[c], acc_t[a][c], 0, 0, 0);
    }

    // pack T[m][q] into current buffer
    #pragma unroll
    for (int a = 0; a < 3; ++a) {
      #pragma unroll
      for (int c = 0; c < 3; ++c) {
        s4v pk;
        #pragma unroll
        for (int r = 0; r < 4; ++r) pk[r] = rne_bf16(acc_t[a][c][r]);
        int m = (wm * 3 + c) * 16 + lane15;
        int q0 = (wq * 3 + a) * 16 + quad * 4;
        *(s4v*)(&buf[m * LDP + q0]) = pk;
      }
    }
    __syncthreads();  // the only barrier per j: T complete

    // mm2: A = T rows (LDS), B = Rs frags (same frags as mm1)
    #pragma unroll
    for (int kc = 0; kc < 6; ++kc) {
      s8v af[3], bf[3];
      #pragma unroll
      for (int a = 0; a < 3; ++a)
        af[a] = *(const s8v*)(&buf[((wq * 3 + a) * 16 + lane15) * LDP + kc * 32 + quad * 8]);
      #pragma unroll
      for (int c = 0; c < 3; ++c)
        bf[c] = *(const s8v*)(rt + (size_t)(((wm * 3 + c) * 6 + kc) * 512) + lane * 8);
      #pragma unroll
      for (int a = 0; a < 3; ++a)
        #pragma unroll
        for (int c = 0; c < 3; ++c)
          acc_y[a][c] = __builtin_amdgcn_mfma_f32_16x16x32_bf16(af[a], bf[c], acc_y[a][c], 0, 0, 0);
    }
  }

  // epilogue: pack y^T[n][m] into rows 0..191 (buf0 region; mm2[7] readers use buf1 - disjoint)
  #pragma unroll
  for (int a = 0; a < 3; ++a) {
    #pragma unroll
    for (int c = 0; c < 3; ++c) {
      s4v pk;
      #pragma unroll
      for (int r = 0; r < 4; ++r) pk[r] = rne_bf16(acc_y[a][c][r]);
      int n = (wm * 3 + c) * 16 + lane15;    // y col
      int m0 = (wq * 3 + a) * 16 + quad * 4; // y row, 4 consecutive
      *(s4v*)(&ldsT[n * LDP + m0]) = pk;
    }
  }
  __syncthreads();
  {
    short* dst = ypart + (size_t)(jg * (BB * CC) + b * CC + i) * (DD * DD);
    #pragma unroll
    for (int it = 0; it < 5; ++it) {
      int c = tid + it * 1024;
      if (c < DD * CH)
        *(s8v*)(dst + (size_t)c * 8) = *(const s8v*)(&ldsT[(c / CH) * LDP + (c % CH) * 8]);
    }
  }
}

// ---------------- stage B1 ----------------
// U[b,j][m_cat][q] = sum_p P_cat[m_cat][p] y[b,j][p][q], split over q-halves.
__global__ __launch_bounds__(512, 1) void stageB1(const short* __restrict__ ypart,
                                                  const short* __restrict__ Pb,
                                                  short* __restrict__ U) {
  __shared__ __align__(16) short ldsYT[96 * LDP];
  __shared__ __align__(16) short ldsP[208 * LDP];
  const int tid = threadIdx.x;
  const int bx = blockIdx.x;
  const int qh = bx & 1, j = (bx >> 1) & 15, b = bx >> 5;
  const int lane15 = tid & 15, quad = (tid & 63) >> 4;
  const int wid = tid >> 6;
  const int wq1 = wid >> 2;
  const int wm1 = wid & 3;

  {
    const short* p0 = ypart + (size_t)(b * CC + j) * (DD * DD) + (size_t)(qh * 96) * DD;
    const short* p1 = p0 + (size_t)(BB * CC) * (DD * DD);
    for (int c = tid; c < 96 * CH; c += 512) {
      s8v v0 = *(const s8v*)(p0 + (size_t)c * 8);
      s8v v1 = *(const s8v*)(p1 + (size_t)c * 8);
      s8v o;
      #pragma unroll
      for (int r = 0; r < 8; ++r) o[r] = rne_bf16(bf2f(v0[r]) + bf2f(v1[r]));
      *(s8v*)(&ldsYT[(c / CH) * LDP + (c % CH) * 8]) = o;
    }
    const s8v z = {0, 0, 0, 0, 0, 0, 0, 0};
    for (int c = tid; c < 208 * CH; c += 512) {
      int row = c / CH, col = c % CH;
      s8v v = z;
      if (row < 200) {
        int oc = row / 50, m = row - oc * 50;
        v = *(const s8v*)(Pb + (size_t)(oc * CC + j) * (OHH * DD) + (size_t)m * DD + col * 8);
      }
      *(s8v*)(&ldsP[row * LDP + col * 8]) = v;
    }
  }
  __syncthreads();

  f32x4 acc[3][4];
  #pragma unroll
  for (int a = 0; a < 3; ++a)
    #pragma unroll
    for (int e = 0; e < 4; ++e) acc[a][e] = (f32x4){0.f, 0.f, 0.f, 0.f};

  #pragma unroll
  for (int kc = 0; kc < 6; ++kc) {
    s8v af[3], bf[4];
    #pragma unroll
    for (int a = 0; a < 3; ++a)
      af[a] = *(const s8v*)(&ldsYT[((wq1 * 3 + a) * 16 + lane15) * LDP + kc * 32 + quad * 8]);
    #pragma unroll
    for (int e = 0; e < 4; ++e) {
      int tn = wm1 * 4 + e;
      if (tn < 13)
        bf[e] = *(const s8v*)(&ldsP[(tn * 16 + lane15) * LDP + kc * 32 + quad * 8]);
    }
    #pragma unroll
    for (int a = 0; a < 3; ++a)
      #pragma unroll
      for (int e = 0; e < 4; ++e)
        if (wm1 * 4 + e < 13)
          acc[a][e] = __builtin_amdgcn_mfma_f32_16x16x32_bf16(af[a], bf[e], acc[a][e], 0, 0, 0);
  }

  short* ub = U + (size_t)(b * CC + j) * (200 * DD);
  #pragma unroll
  for (int a = 0; a < 3; ++a) {
    #pragma unroll
    for (int e = 0; e < 4; ++e) {
      int tn = wm1 * 4 + e;
      if (tn < 13) {
        int m = tn * 16 + lane15;
        if (m < 200) {
          s4v pk;
          #pragma unroll
          for (int r = 0; r < 4; ++r) pk[r] = rne_bf16(acc[a][e][r]);
          int q0 = qh * 96 + (wq1 * 3 + a) * 16 + quad * 4;
          *(s4v*)(ub + (size_t)m * DD + q0) = pk;
        }
      }
    }
  }
}

// ---------------- stage B2 ----------------
__global__ __launch_bounds__(256, 2) void stageB2(const short* __restrict__ U,
                                                  const short* __restrict__ PTTb,
                                                  float* __restrict__ out) {
  __shared__ __align__(16) short ldsU[64 * LDP];
  __shared__ __align__(16) short ldsPT[64 * LDP];
  const int tid = threadIdx.x;
  const int bx = blockIdx.x;
  const int jg = bx & 3, nq = (bx >> 2) & 3, oc = (bx >> 4) & 3, b = bx >> 6;
  const int lane15 = tid & 15, quad = (tid & 63) >> 4;
  const int wid = tid >> 6;
  const int wm2 = wid & 1, wn2 = wid >> 1;

  f32x4 acc[2][2];
  #pragma unroll
  for (int a = 0; a < 2; ++a)
    #pragma unroll
    for (int e = 0; e < 2; ++e) acc[a][e] = (f32x4){0.f, 0.f, 0.f, 0.f};

  const s8v z = {0, 0, 0, 0, 0, 0, 0, 0};
  for (int jj = 0; jj < 4; ++jj) {
    const int j = jg * 4 + jj;
    __syncthreads();
    {
      const short* us = U + (size_t)((b * CC + j) * 200 + oc * 50) * DD;
      const short* ps = PTTb + (size_t)(oc * CC + j) * (OWW * DD) + (size_t)(nq * 50) * DD;
      for (int c = tid; c < 64 * CH; c += 256) {
        int row = c / CH, col = c % CH;
        s8v vu = (row < 50) ? *(const s8v*)(us + (size_t)row * DD + col * 8) : z;
        s8v vp = (row < 50) ? *(const s8v*)(ps + (size_t)row * DD + col * 8) : z;
        *(s8v*)(&ldsU[row * LDP + col * 8]) = vu;
        *(s8v*)(&ldsPT[row * LDP + col * 8]) = vp;
      }
    }
    __syncthreads();

    #pragma unroll
    for (int kc = 0; kc < 6; ++kc) {
      s8v af[2], bf[2];
      #pragma unroll
      for (int a = 0; a < 2; ++a)
        af[a] = *(const s8v*)(&ldsU[((wm2 * 2 + a) * 16 + lane15) * LDP + kc * 32 + quad * 8]);
      #pragma unroll
      for (int e = 0; e < 2; ++e)
        bf[e] = *(const s8v*)(&ldsPT[((wn2 * 2 + e) * 16 + lane15) * LDP + kc * 32 + quad * 8]);
      #pragma unroll
      for (int a = 0; a < 2; ++a)
        #pragma unroll
        for (int e = 0; e < 2; ++e)
          acc[a][e] = __builtin_amdgcn_mfma_f32_16x16x32_bf16(af[a], bf[e], acc[a][e], 0, 0, 0);
    }
  }

  float* dst = out + (size_t)(b * OCC + oc) * (OHH * OWW);
  #pragma unroll
  for (int a = 0; a < 2; ++a) {
    #pragma unroll
    for (int e = 0; e < 2; ++e) {
      int n = (wn2 * 2 + e) * 16 + lane15;
      if (n < 50) {
        #pragma unroll
        for (int r = 0; r < 4; ++r) {
          int m = (wm2 * 2 + a) * 16 + quad * 4 + r;
          if (m < OHH)
            atomicAdd(&dst[(size_t)m * OWW + nq * 50 + n], acc[a][e][r]);
        }
      }
    }
  }
}

// ---------------- launcher ----------------

extern "C" void kernel_launch(void* const* d_in, const int* in_sizes, int n_in,
                              void* d_out, int out_size, void* d_ws, size_t ws_size,
                              hipStream_t stream) {
  const float* x  = (const float*)d_in[0];
  const float* R  = (const float*)d_in[1];
  const float* P  = (const float*)d_in[2];
  const float* PT = (const float*)d_in[3];
  float* out = (float*)d_out;

  short* W = (short*)d_ws;
  const size_t nR    = (size_t)CC * CC * DD * DD;    // 9,437,184
  const size_t nX    = (size_t)BB * CC * DD * DD;    // 4,718,592
  const size_t nP    = (size_t)OCC * CC * OHH * DD;  // 614,400
  const size_t nPT   = (size_t)OCC * CC * OWW * DD;  // 2,457,600
  short* Rs    = W;
  short* Xs    = Rs + nR;
  short* Pb    = Xs + nX;
  short* PTTb  = Pb + nP;
  short* ypart = PTTb + nPT;                          // 2 * nX
  short* Ubuf  = ypart + 2 * nX;                      // 128 * 200 * 192

  prep_all<<<PREP_TOTAL, 256, 0, stream>>>(R, Rs, x, Xs, P, Pb, PT, PTTb);
  hipMemsetAsync(d_out, 0, (size_t)out_size * sizeof(float), stream);
  stageA<<<BB * CC * 2, 1024, 0, stream>>>(Rs, Xs, ypart);
  stageB1<<<BB * CC * 2, 512, 0, stream>>>(ypart, Pb, Ubuf);
  stageB2<<<BB * OCC * 4 * 4, 256, 0, stream>>>(Ubuf, PTTb, out);
}